// Round 1
// baseline (531.883 us; speedup 1.0000x reference)
//
#include <hip/hip_runtime.h>
#include <hip/hip_bf16.h>

#define T_ 2048
#define D_ 2048
#define H_ 16
#define HD_ 128

typedef __hip_bfloat16 bf16;
using bf16x8 = __attribute__((ext_vector_type(8))) short;   // 8 bf16 = 4 VGPRs
using f32x4  = __attribute__((ext_vector_type(4))) float;

#define GLL16(g, l) __builtin_amdgcn_global_load_lds( \
    (const __attribute__((address_space(1))) void*)(g), \
    (__attribute__((address_space(3))) void*)(l), 16, 0, 0)

__device__ __forceinline__ f32x4 mfma16(bf16x8 a, bf16x8 b, f32x4 c) {
    return __builtin_amdgcn_mfma_f32_16x16x32_bf16(a, b, c, 0, 0, 0);
}

// ---------- cast fp32 -> bf16: 6 uniform chunks of 4194304 elems ----------
__global__ __launch_bounds__(256) void cast6(
    const float* __restrict__ s0, const float* __restrict__ s1,
    const float* __restrict__ s2, const float* __restrict__ s3,
    const float* __restrict__ s4, const float* __restrict__ s5,
    bf16* __restrict__ dst)
{
    int z = blockIdx.y;
    const float* s = (z == 0) ? s0 : (z == 1) ? s1 : (z == 2) ? s2
                   : (z == 3) ? s3 : (z == 4) ? s4 : s5;
    long i = ((long)blockIdx.x * 256 + threadIdx.x) * 8;
    float4 a = *(const float4*)(s + i);
    float4 b = *(const float4*)(s + i + 4);
    union { bf16 h[8]; int4 v; } u;
    u.h[0] = __float2bfloat16(a.x); u.h[1] = __float2bfloat16(a.y);
    u.h[2] = __float2bfloat16(a.z); u.h[3] = __float2bfloat16(a.w);
    u.h[4] = __float2bfloat16(b.x); u.h[5] = __float2bfloat16(b.y);
    u.h[6] = __float2bfloat16(b.z); u.h[7] = __float2bfloat16(b.w);
    *(int4*)(dst + (long)z * 4194304 + i) = u.v;
}

// ---------- QKV projection: C[m][n] = sum_k xb[m][k]*W[n][k], out -> [B,H,T,HD] bf16 ----------
__global__ __launch_bounds__(256) void gemm_qkv(
    const bf16* __restrict__ xb,
    const bf16* __restrict__ wq, const bf16* __restrict__ wk, const bf16* __restrict__ wv,
    bf16* __restrict__ Qo, bf16* __restrict__ Ko, bf16* __restrict__ Vo)
{
    __shared__ bf16 As[128*32];
    __shared__ bf16 Bs[128*32];
    int z = blockIdx.z;
    const bf16* W = (z == 0) ? wq : (z == 1) ? wk : wv;
    bf16* out = (z == 0) ? Qo : (z == 1) ? Ko : Vo;
    int bn = blockIdx.x, bm = blockIdx.y;
    int tid = threadIdx.x, lane = tid & 63, w = tid >> 6;
    int wm = w >> 1, wn = w & 1;
    const bf16* Abase = xb + (long)bm * 128 * D_;
    const bf16* Bbase = W  + (long)bn * 128 * D_;
    int srow = w*16 + (lane >> 2);
    int scol = (lane & 3) * 8;

    f32x4 acc[4][4];
    #pragma unroll
    for (int i = 0; i < 4; ++i)
        #pragma unroll
        for (int j = 0; j < 4; ++j) acc[i][j] = f32x4{0.f,0.f,0.f,0.f};

    for (int kt = 0; kt < D_/32; ++kt) {
        const bf16* Ag = Abase + kt*32;
        const bf16* Bg = Bbase + kt*32;
        GLL16(Ag + (long)srow*D_ + scol,        As + w*512);
        GLL16(Ag + (long)(srow+64)*D_ + scol,   As + 2048 + w*512);
        GLL16(Bg + (long)srow*D_ + scol,        Bs + w*512);
        GLL16(Bg + (long)(srow+64)*D_ + scol,   Bs + 2048 + w*512);
        __syncthreads();
        bf16x8 af[4], bfr[4];
        #pragma unroll
        for (int mt = 0; mt < 4; ++mt)
            af[mt] = *(const bf16x8*)&As[(wm*64 + mt*16 + (lane & 15))*32 + (lane >> 4)*8];
        #pragma unroll
        for (int nt = 0; nt < 4; ++nt)
            bfr[nt] = *(const bf16x8*)&Bs[(wn*64 + nt*16 + (lane & 15))*32 + (lane >> 4)*8];
        #pragma unroll
        for (int mt = 0; mt < 4; ++mt)
            #pragma unroll
            for (int nt = 0; nt < 4; ++nt)
                acc[mt][nt] = mfma16(af[mt], bfr[nt], acc[mt][nt]);
        __syncthreads();
    }
    int mlo = bm*128 + wm*64;
    int nlo = bn*128 + wn*64;
    #pragma unroll
    for (int mt = 0; mt < 4; ++mt) {
        #pragma unroll
        for (int nt = 0; nt < 4; ++nt) {
            int n = nlo + nt*16 + (lane & 15);
            int h = n >> 7, hd = n & 127;
            #pragma unroll
            for (int r = 0; r < 4; ++r) {
                int m = mlo + mt*16 + (lane >> 4)*4 + r;     // C/D: row=(l>>4)*4+r, col=l&15
                int b = m >> 11, t = m & 2047;
                out[(((long)(b*H_ + h))*T_ + t)*HD_ + hd] = __float2bfloat16(acc[mt][nt][r]);
            }
        }
    }
}

// ---------- causal flash attention: grid (bm=16, bh=32), block 256 ----------
__global__ __launch_bounds__(256) void attn(
    const bf16* __restrict__ Qm, const bf16* __restrict__ Km, const bf16* __restrict__ Vm,
    bf16* __restrict__ Om)   // Om in [B,T,D]
{
    __shared__ bf16 Ks[64*136];     // K tile, +8 pad (row 272B: 16B-aligned, 4-bank rotate)
    __shared__ bf16 Vt[128*72];     // V tile transposed Vt[d][n], +8 pad (row 144B)
    __shared__ bf16 Ps[128*72];     // P round-trip, same padding
    int bm = blockIdx.x, bh = blockIdx.y;
    int tid = threadIdx.x, lane = tid & 63, w = tid >> 6;
    const float scale = 0.08838834764831845f;   // 1/sqrt(128)
    const float L2E   = 1.4426950408889634f;
    const bf16* Qb = Qm + (long)bh*T_*HD_;
    const bf16* Kb = Km + (long)bh*T_*HD_;
    const bf16* Vb = Vm + (long)bh*T_*HD_;
    int m0 = bm*128 + w*32;                      // this wave's 32 Q rows

    bf16x8 qf[2][4];                             // Q fragments live in regs for whole block
    #pragma unroll
    for (int mt = 0; mt < 2; ++mt)
        #pragma unroll
        for (int ks = 0; ks < 4; ++ks)
            qf[mt][ks] = *(const bf16x8*)(Qb + (long)(m0 + mt*16 + (lane & 15))*HD_ + ks*32 + (lane >> 4)*8);

    f32x4 oacc[2][8];
    #pragma unroll
    for (int mt = 0; mt < 2; ++mt)
        #pragma unroll
        for (int dt = 0; dt < 8; ++dt) oacc[mt][dt] = f32x4{0.f,0.f,0.f,0.f};
    float mrow[2][4], lrow[2][4];
    #pragma unroll
    for (int mt = 0; mt < 2; ++mt)
        #pragma unroll
        for (int r = 0; r < 4; ++r) { mrow[mt][r] = -1e30f; lrow[mt][r] = 0.f; }

    int njt = 2*bm + 2;                          // causal: K/V tiles 0..2bm+1
    for (int j = 0; j < njt; ++j) {
        int j0 = j*64;
        __syncthreads();                         // protect K/Vt overwrite
        #pragma unroll
        for (int i = 0; i < 4; ++i) {            // stage K [64][128]
            int ch = i*256 + tid;
            int row = ch >> 4, cg = ch & 15;
            *(bf16x8*)&Ks[row*136 + cg*8] =
                *(const bf16x8*)(Kb + (long)(j0 + row)*HD_ + cg*8);
        }
        #pragma unroll
        for (int i = 0; i < 4; ++i) {            // stage V transposed: Vt[d][n]
            int dg = w + i*4;                    // wave-uniform d-group
            union { bf16 h[8]; bf16x8 v; } u;
            u.v = *(const bf16x8*)(Vb + (long)(j0 + lane)*HD_ + dg*8);
            #pragma unroll
            for (int jj = 0; jj < 8; ++jj)
                Vt[(dg*8 + jj)*72 + lane] = u.h[jj];
        }
        __syncthreads();
        // S = Q K^T  (32 rows x 64 cols per wave)
        f32x4 s[2][4];
        #pragma unroll
        for (int mt = 0; mt < 2; ++mt)
            #pragma unroll
            for (int nt = 0; nt < 4; ++nt) s[mt][nt] = f32x4{0.f,0.f,0.f,0.f};
        #pragma unroll
        for (int ks = 0; ks < 4; ++ks) {
            bf16x8 kf[4];
            #pragma unroll
            for (int nt = 0; nt < 4; ++nt)
                kf[nt] = *(const bf16x8*)&Ks[(nt*16 + (lane & 15))*136 + ks*32 + (lane >> 4)*8];
            #pragma unroll
            for (int mt = 0; mt < 2; ++mt)
                #pragma unroll
                for (int nt = 0; nt < 4; ++nt)
                    s[mt][nt] = mfma16(qf[mt][ks], kf[nt], s[mt][nt]);
        }
        // online softmax (C-layout: row spread over 16 lanes of same quad-group)
        #pragma unroll
        for (int mt = 0; mt < 2; ++mt) {
            #pragma unroll
            for (int r = 0; r < 4; ++r) {
                int mg = m0 + mt*16 + (lane >> 4)*4 + r;   // global Q row
                float sv[4], rmax = -1e30f;
                #pragma unroll
                for (int nt = 0; nt < 4; ++nt) {
                    int n = j0 + nt*16 + (lane & 15);
                    float x = s[mt][nt][r] * scale;
                    x = (n <= mg) ? x : -1e30f;            // causal mask
                    sv[nt] = x;
                    rmax = fmaxf(rmax, x);
                }
                #pragma unroll
                for (int d = 1; d < 16; d <<= 1)
                    rmax = fmaxf(rmax, __shfl_xor(rmax, d, 64));
                float mnew = fmaxf(mrow[mt][r], rmax);
                float alpha = exp2f((mrow[mt][r] - mnew) * L2E);
                mrow[mt][r] = mnew;
                float rsum = 0.f;
                int prow = w*32 + mt*16 + (lane >> 4)*4 + r;
                #pragma unroll
                for (int nt = 0; nt < 4; ++nt) {
                    float p = exp2f((sv[nt] - mnew) * L2E);
                    rsum += p;
                    Ps[prow*72 + nt*16 + (lane & 15)] = __float2bfloat16(p);
                }
                #pragma unroll
                for (int d = 1; d < 16; d <<= 1)
                    rsum += __shfl_xor(rsum, d, 64);
                lrow[mt][r] = lrow[mt][r]*alpha + rsum;
                #pragma unroll
                for (int dt = 0; dt < 8; ++dt) oacc[mt][dt][r] *= alpha;
            }
        }
        // O += P V   (P via LDS: C-layout -> A-layout; V via Vt: ds_read_b128)
        #pragma unroll
        for (int kn = 0; kn < 2; ++kn) {
            bf16x8 pf[2], vf[8];
            #pragma unroll
            for (int mt = 0; mt < 2; ++mt)
                pf[mt] = *(const bf16x8*)&Ps[(w*32 + mt*16 + (lane & 15))*72 + kn*32 + (lane >> 4)*8];
            #pragma unroll
            for (int dt = 0; dt < 8; ++dt)
                vf[dt] = *(const bf16x8*)&Vt[(dt*16 + (lane & 15))*72 + kn*32 + (lane >> 4)*8];
            #pragma unroll
            for (int mt = 0; mt < 2; ++mt)
                #pragma unroll
                for (int dt = 0; dt < 8; ++dt)
                    oacc[mt][dt] = mfma16(pf[mt], vf[dt], oacc[mt][dt]);
        }
    }
    // epilogue: normalize, write bf16 into [B,T,D]
    int b = bh >> 4, h = bh & 15;
    #pragma unroll
    for (int mt = 0; mt < 2; ++mt) {
        #pragma unroll
        for (int r = 0; r < 4; ++r) {
            float inv = 1.f / lrow[mt][r];
            int t = m0 + mt*16 + (lane >> 4)*4 + r;
            #pragma unroll
            for (int dt = 0; dt < 8; ++dt) {
                int d = dt*16 + (lane & 15);
                Om[((long)(b*T_ + t))*D_ + h*HD_ + d] = __float2bfloat16(oacc[mt][dt][r] * inv);
            }
        }
    }
}

// ---------- output projection: fp32 out = O @ Wo^T + bo ----------
__global__ __launch_bounds__(256) void gemm_out(
    const bf16* __restrict__ Ab, const bf16* __restrict__ Wob,
    const float* __restrict__ bo, float* __restrict__ out)
{
    __shared__ bf16 As[128*32];
    __shared__ bf16 Bs[128*32];
    int bn = blockIdx.x, bm = blockIdx.y;
    int tid = threadIdx.x, lane = tid & 63, w = tid >> 6;
    int wm = w >> 1, wn = w & 1;
    const bf16* Abase = Ab  + (long)bm * 128 * D_;
    const bf16* Bbase = Wob + (long)bn * 128 * D_;
    int srow = w*16 + (lane >> 2);
    int scol = (lane & 3) * 8;

    f32x4 acc[4][4];
    #pragma unroll
    for (int i = 0; i < 4; ++i)
        #pragma unroll
        for (int j = 0; j < 4; ++j) acc[i][j] = f32x4{0.f,0.f,0.f,0.f};

    for (int kt = 0; kt < D_/32; ++kt) {
        const bf16* Ag = Abase + kt*32;
        const bf16* Bg = Bbase + kt*32;
        GLL16(Ag + (long)srow*D_ + scol,        As + w*512);
        GLL16(Ag + (long)(srow+64)*D_ + scol,   As + 2048 + w*512);
        GLL16(Bg + (long)srow*D_ + scol,        Bs + w*512);
        GLL16(Bg + (long)(srow+64)*D_ + scol,   Bs + 2048 + w*512);
        __syncthreads();
        bf16x8 af[4], bfr[4];
        #pragma unroll
        for (int mt = 0; mt < 4; ++mt)
            af[mt] = *(const bf16x8*)&As[(wm*64 + mt*16 + (lane & 15))*32 + (lane >> 4)*8];
        #pragma unroll
        for (int nt = 0; nt < 4; ++nt)
            bfr[nt] = *(const bf16x8*)&Bs[(wn*64 + nt*16 + (lane & 15))*32 + (lane >> 4)*8];
        #pragma unroll
        for (int mt = 0; mt < 4; ++mt)
            #pragma unroll
            for (int nt = 0; nt < 4; ++nt)
                acc[mt][nt] = mfma16(af[mt], bfr[nt], acc[mt][nt]);
        __syncthreads();
    }
    int mlo = bm*128 + wm*64;
    int nlo = bn*128 + wn*64;
    #pragma unroll
    for (int mt = 0; mt < 4; ++mt) {
        #pragma unroll
        for (int nt = 0; nt < 4; ++nt) {
            int n = nlo + nt*16 + (lane & 15);
            float bias = bo[n];
            #pragma unroll
            for (int r = 0; r < 4; ++r) {
                int m = mlo + mt*16 + (lane >> 4)*4 + r;
                out[(long)m*D_ + n] = acc[mt][nt][r] + bias;
            }
        }
    }
}

extern "C" void kernel_launch(void* const* d_in, const int* in_sizes, int n_in,
                              void* d_out, int out_size, void* d_ws, size_t ws_size,
                              hipStream_t stream) {
    const float* x  = (const float*)d_in[0];
    const float* Wq = (const float*)d_in[1];
    const float* Wk = (const float*)d_in[2];
    const float* Wv = (const float*)d_in[3];
    const float* Wo = (const float*)d_in[4];
    const float* bo = (const float*)d_in[5];
    float* out = (float*)d_out;

    bf16* ws  = (bf16*)d_ws;
    bf16* xb  = ws;                    // 8388608 elems [B*T, D], later reused as attn output O
    bf16* wqb = ws + 8388608L;         // 4194304 each
    bf16* wkb = ws + 12582912L;
    bf16* wvb = ws + 16777216L;
    bf16* wob = ws + 20971520L;
    bf16* Qb  = ws + 25165824L;        // [B,H,T,HD] 8388608 each
    bf16* Kb  = ws + 33554432L;
    bf16* Vb  = ws + 41943040L;
    bf16* Ob  = xb;                    // reuse (xb dead after gemm_qkv)
    // total ws use: 50331648 * 2 B = ~96 MB

    cast6<<<dim3(2048, 6), 256, 0, stream>>>(x, x + 4194304L, Wq, Wk, Wv, Wo, ws);
    gemm_qkv<<<dim3(16, 32, 3), 256, 0, stream>>>(xb, wqb, wkb, wvb, Qb, Kb, Vb);
    attn<<<dim3(16, 32), 256, 0, stream>>>(Qb, Kb, Vb, Ob);
    gemm_out<<<dim3(16, 32), 256, 0, stream>>>(Ob, wob, bo, out);
}

// Round 2
// 393.847 us; speedup vs baseline: 1.3505x; 1.3505x over previous
//
#include <hip/hip_runtime.h>
#include <hip/hip_bf16.h>

#define T_ 2048
#define D_ 2048
#define H_ 16
#define HD_ 128

typedef __hip_bfloat16 bf16;
using bf16x8 = __attribute__((ext_vector_type(8))) short;   // 8 bf16 = 4 VGPRs
using f32x4  = __attribute__((ext_vector_type(4))) float;

#define GLL16(g, l) __builtin_amdgcn_global_load_lds( \
    (const __attribute__((address_space(1))) void*)(g), \
    (__attribute__((address_space(3))) void*)(l), 16, 0, 0)

__device__ __forceinline__ f32x4 mfma16(bf16x8 a, bf16x8 b, f32x4 c) {
    return __builtin_amdgcn_mfma_f32_16x16x32_bf16(a, b, c, 0, 0, 0);
}

// ---------- cast fp32 -> bf16: 6 uniform chunks of 4194304 elems ----------
__global__ __launch_bounds__(256) void cast6(
    const float* __restrict__ s0, const float* __restrict__ s1,
    const float* __restrict__ s2, const float* __restrict__ s3,
    const float* __restrict__ s4, const float* __restrict__ s5,
    bf16* __restrict__ dst)
{
    int z = blockIdx.y;
    const float* s = (z == 0) ? s0 : (z == 1) ? s1 : (z == 2) ? s2
                   : (z == 3) ? s3 : (z == 4) ? s4 : s5;
    long i = ((long)blockIdx.x * 256 + threadIdx.x) * 8;
    float4 a = *(const float4*)(s + i);
    float4 b = *(const float4*)(s + i + 4);
    union { bf16 h[8]; int4 v; } u;
    u.h[0] = __float2bfloat16(a.x); u.h[1] = __float2bfloat16(a.y);
    u.h[2] = __float2bfloat16(a.z); u.h[3] = __float2bfloat16(a.w);
    u.h[4] = __float2bfloat16(b.x); u.h[5] = __float2bfloat16(b.y);
    u.h[6] = __float2bfloat16(b.z); u.h[7] = __float2bfloat16(b.w);
    *(int4*)(dst + (long)z * 4194304 + i) = u.v;
}

// ---------- QKV projection: C[m][n] = sum_k xb[m][k]*W[n][k], out -> [B,H,T,HD] bf16 ----------
__global__ __launch_bounds__(256) void gemm_qkv(
    const bf16* __restrict__ xb,
    const bf16* __restrict__ wq, const bf16* __restrict__ wk, const bf16* __restrict__ wv,
    bf16* __restrict__ Qo, bf16* __restrict__ Ko, bf16* __restrict__ Vo)
{
    __shared__ bf16 As[128*32];
    __shared__ bf16 Bs[128*32];
    int z = blockIdx.z;
    const bf16* W = (z == 0) ? wq : (z == 1) ? wk : wv;
    bf16* out = (z == 0) ? Qo : (z == 1) ? Ko : Vo;
    int bn = blockIdx.x, bm = blockIdx.y;
    int tid = threadIdx.x, lane = tid & 63, w = tid >> 6;
    int wm = w >> 1, wn = w & 1;
    const bf16* Abase = xb + (long)bm * 128 * D_;
    const bf16* Bbase = W  + (long)bn * 128 * D_;
    int srow = w*16 + (lane >> 2);
    int scol = (lane & 3) * 8;

    f32x4 acc[4][4];
    #pragma unroll
    for (int i = 0; i < 4; ++i)
        #pragma unroll
        for (int j = 0; j < 4; ++j) acc[i][j] = f32x4{0.f,0.f,0.f,0.f};

    for (int kt = 0; kt < D_/32; ++kt) {
        const bf16* Ag = Abase + kt*32;
        const bf16* Bg = Bbase + kt*32;
        GLL16(Ag + (long)srow*D_ + scol,        As + w*512);
        GLL16(Ag + (long)(srow+64)*D_ + scol,   As + 2048 + w*512);
        GLL16(Bg + (long)srow*D_ + scol,        Bs + w*512);
        GLL16(Bg + (long)(srow+64)*D_ + scol,   Bs + 2048 + w*512);
        __syncthreads();
        bf16x8 af[4], bfr[4];
        #pragma unroll
        for (int mt = 0; mt < 4; ++mt)
            af[mt] = *(const bf16x8*)&As[(wm*64 + mt*16 + (lane & 15))*32 + (lane >> 4)*8];
        #pragma unroll
        for (int nt = 0; nt < 4; ++nt)
            bfr[nt] = *(const bf16x8*)&Bs[(wn*64 + nt*16 + (lane & 15))*32 + (lane >> 4)*8];
        #pragma unroll
        for (int mt = 0; mt < 4; ++mt)
            #pragma unroll
            for (int nt = 0; nt < 4; ++nt)
                acc[mt][nt] = mfma16(af[mt], bfr[nt], acc[mt][nt]);
        __syncthreads();
    }
    int mlo = bm*128 + wm*64;
    int nlo = bn*128 + wn*64;
    #pragma unroll
    for (int mt = 0; mt < 4; ++mt) {
        #pragma unroll
        for (int nt = 0; nt < 4; ++nt) {
            int n = nlo + nt*16 + (lane & 15);
            int h = n >> 7, hd = n & 127;
            #pragma unroll
            for (int r = 0; r < 4; ++r) {
                int m = mlo + mt*16 + (lane >> 4)*4 + r;     // C/D: row=(l>>4)*4+r, col=l&15
                int b = m >> 11, t = m & 2047;
                out[(((long)(b*H_ + h))*T_ + t)*HD_ + hd] = __float2bfloat16(acc[mt][nt][r]);
            }
        }
    }
}

// ---------- causal flash attention, fixed-max softmax, K/V register prefetch ----------
// grid: 512 1-D blocks (heavy-first), block 256
__global__ __launch_bounds__(256) void attn(
    const bf16* __restrict__ Qm, const bf16* __restrict__ Km, const bf16* __restrict__ Vm,
    bf16* __restrict__ Om)   // Om in [B,T,D]
{
    __shared__ bf16 Ks[64*136];     // K tile [pos][d], +8 pad
    __shared__ bf16 Vt[128*72];     // V tile transposed Vt[d][pos], +8 pad
    __shared__ bf16 Ps[128*72];     // P round-trip (per-wave private rows)
    int bm = 15 - (blockIdx.x >> 5);        // heavy blocks dispatch first
    int bh = blockIdx.x & 31;
    int tid = threadIdx.x, lane = tid & 63, w = tid >> 6;
    const float c1 = 0.12754012780914427f;  // (1/sqrt(128)) * log2(e)
    const float c2 = 23.083120654223414f;   // 16 * log2(e)  (fixed max M=16)
    const bf16* Qb = Qm + (long)bh*T_*HD_;
    const bf16* Kb = Km + (long)bh*T_*HD_;
    const bf16* Vb = Vm + (long)bh*T_*HD_;
    int m0 = bm*128 + w*32;                 // this wave's 32 Q rows

    // Q fragments in regs for whole block
    bf16x8 qf[2][4];
    #pragma unroll
    for (int mt = 0; mt < 2; ++mt)
        #pragma unroll
        for (int ks = 0; ks < 4; ++ks)
            qf[mt][ks] = *(const bf16x8*)(Qb + (long)(m0 + mt*16 + (lane & 15))*HD_ + ks*32 + (lane >> 4)*8);

    // ones B-fragment: B[k][0]=1 -> row-sum of P rides the MFMA pipe
    bf16x8 onesB;
    {
        short v1 = ((lane & 15) == 0) ? (short)0x3F80 : (short)0;
        #pragma unroll
        for (int jj = 0; jj < 8; ++jj) onesB[jj] = v1;
    }

    f32x4 oacc[2][8];
    f32x4 lacc[2];
    #pragma unroll
    for (int mt = 0; mt < 2; ++mt) {
        lacc[mt] = f32x4{0.f,0.f,0.f,0.f};
        #pragma unroll
        for (int dt = 0; dt < 8; ++dt) oacc[mt][dt] = f32x4{0.f,0.f,0.f,0.f};
    }

    int krow = (tid >> 4);          // + i*16
    int kcg  = tid & 15;
    int njt = 2*bm + 2;             // causal: K/V tiles 0..2bm+1

    // prefetch tile 0 into regs
    bf16x8 kreg[4], vreg[4];
    #pragma unroll
    for (int i = 0; i < 4; ++i) {
        kreg[i] = *(const bf16x8*)(Kb + (long)(i*16 + krow)*HD_ + kcg*8);
        vreg[i] = *(const bf16x8*)(Vb + (long)lane*HD_ + (w + i*4)*8);
    }

    for (int j = 0; j < njt; ++j) {
        int j0 = j*64;
        __syncthreads();                         // all waves done reading prev Ks/Vt
        #pragma unroll
        for (int i = 0; i < 4; ++i)              // K regs -> LDS (vector)
            *(bf16x8*)&Ks[(i*16 + krow)*136 + kcg*8] = kreg[i];
        #pragma unroll
        for (int i = 0; i < 4; ++i) {            // V regs -> LDS transposed (scatter)
            int dg = w + i*4;
            union { bf16 h[8]; bf16x8 v; } u;
            u.v = vreg[i];
            #pragma unroll
            for (int jj = 0; jj < 8; ++jj)
                Vt[(dg*8 + jj)*72 + lane] = u.h[jj];
        }
        __syncthreads();

        // issue prefetch for tile j+1 (overlaps with compute below)
        if (j + 1 < njt) {
            int jn0 = j0 + 64;
            #pragma unroll
            for (int i = 0; i < 4; ++i) {
                kreg[i] = *(const bf16x8*)(Kb + (long)(jn0 + i*16 + krow)*HD_ + kcg*8);
                vreg[i] = *(const bf16x8*)(Vb + (long)(jn0 + lane)*HD_ + (w + i*4)*8);
            }
        }

        bool anyv  = (j0 <= m0 + 31);            // wave-uniform: any visible column?
        if (anyv) {
            bool bmask = (j0 + 63 > m0);         // wave-uniform: boundary tile?
            // S = Q K^T  (32 rows x 64 cols per wave)
            f32x4 s[2][4];
            #pragma unroll
            for (int mt = 0; mt < 2; ++mt)
                #pragma unroll
                for (int nt = 0; nt < 4; ++nt) s[mt][nt] = f32x4{0.f,0.f,0.f,0.f};
            #pragma unroll
            for (int ks = 0; ks < 4; ++ks) {
                bf16x8 kf[4];
                #pragma unroll
                for (int nt = 0; nt < 4; ++nt)
                    kf[nt] = *(const bf16x8*)&Ks[(nt*16 + (lane & 15))*136 + ks*32 + (lane >> 4)*8];
                #pragma unroll
                for (int mt = 0; mt < 2; ++mt)
                    #pragma unroll
                    for (int nt = 0; nt < 4; ++nt)
                        s[mt][nt] = mfma16(qf[mt][ks], kf[nt], s[mt][nt]);
            }
            // fixed-max softmax: p = exp2(s*c1 - c2); no reductions, no rescale
            #pragma unroll
            for (int mt = 0; mt < 2; ++mt) {
                #pragma unroll
                for (int nt = 0; nt < 4; ++nt) {
                    int n = j0 + nt*16 + (lane & 15);
                    #pragma unroll
                    for (int r = 0; r < 4; ++r) {
                        float x = s[mt][nt][r] * c1 - c2;
                        if (bmask) {
                            int mg = m0 + mt*16 + (lane >> 4)*4 + r;
                            x = (n <= mg) ? x : -1e30f;
                        }
                        float p = exp2f(x);
                        int prow = w*32 + mt*16 + (lane >> 4)*4 + r;
                        Ps[prow*72 + nt*16 + (lane & 15)] = __float2bfloat16(p);
                    }
                }
            }
            // O += P V ; l += P 1   (P via LDS C->A layout; V via Vt: ds_read_b128)
            #pragma unroll
            for (int kn = 0; kn < 2; ++kn) {
                bf16x8 pf[2], vf[8];
                #pragma unroll
                for (int mt = 0; mt < 2; ++mt)
                    pf[mt] = *(const bf16x8*)&Ps[(w*32 + mt*16 + (lane & 15))*72 + kn*32 + (lane >> 4)*8];
                #pragma unroll
                for (int dt = 0; dt < 8; ++dt)
                    vf[dt] = *(const bf16x8*)&Vt[(dt*16 + (lane & 15))*72 + kn*32 + (lane >> 4)*8];
                #pragma unroll
                for (int mt = 0; mt < 2; ++mt)
                    lacc[mt] = mfma16(pf[mt], onesB, lacc[mt]);
                #pragma unroll
                for (int mt = 0; mt < 2; ++mt)
                    #pragma unroll
                    for (int dt = 0; dt < 8; ++dt)
                        oacc[mt][dt] = mfma16(pf[mt], vf[dt], oacc[mt][dt]);
            }
        }
    }
    // epilogue: broadcast row sums (col 0 lives at lane&15==0), normalize, store
    int b = bh >> 4, h = bh & 15;
    #pragma unroll
    for (int mt = 0; mt < 2; ++mt) {
        #pragma unroll
        for (int r = 0; r < 4; ++r) {
            float l = __shfl(lacc[mt][r], lane & 48, 64);
            float inv = 1.f / l;
            int t = m0 + mt*16 + (lane >> 4)*4 + r;
            #pragma unroll
            for (int dt = 0; dt < 8; ++dt) {
                int d = dt*16 + (lane & 15);
                Om[((long)(b*T_ + t))*D_ + h*HD_ + d] = __float2bfloat16(oacc[mt][dt][r] * inv);
            }
        }
    }
}

// ---------- output projection: fp32 out = O @ Wo^T + bo ----------
__global__ __launch_bounds__(256) void gemm_out(
    const bf16* __restrict__ Ab, const bf16* __restrict__ Wob,
    const float* __restrict__ bo, float* __restrict__ out)
{
    __shared__ bf16 As[128*32];
    __shared__ bf16 Bs[128*32];
    int bn = blockIdx.x, bm = blockIdx.y;
    int tid = threadIdx.x, lane = tid & 63, w = tid >> 6;
    int wm = w >> 1, wn = w & 1;
    const bf16* Abase = Ab  + (long)bm * 128 * D_;
    const bf16* Bbase = Wob + (long)bn * 128 * D_;
    int srow = w*16 + (lane >> 2);
    int scol = (lane & 3) * 8;

    f32x4 acc[4][4];
    #pragma unroll
    for (int i = 0; i < 4; ++i)
        #pragma unroll
        for (int j = 0; j < 4; ++j) acc[i][j] = f32x4{0.f,0.f,0.f,0.f};

    for (int kt = 0; kt < D_/32; ++kt) {
        const bf16* Ag = Abase + kt*32;
        const bf16* Bg = Bbase + kt*32;
        GLL16(Ag + (long)srow*D_ + scol,        As + w*512);
        GLL16(Ag + (long)(srow+64)*D_ + scol,   As + 2048 + w*512);
        GLL16(Bg + (long)srow*D_ + scol,        Bs + w*512);
        GLL16(Bg + (long)(srow+64)*D_ + scol,   Bs + 2048 + w*512);
        __syncthreads();
        bf16x8 af[4], bfr[4];
        #pragma unroll
        for (int mt = 0; mt < 4; ++mt)
            af[mt] = *(const bf16x8*)&As[(wm*64 + mt*16 + (lane & 15))*32 + (lane >> 4)*8];
        #pragma unroll
        for (int nt = 0; nt < 4; ++nt)
            bfr[nt] = *(const bf16x8*)&Bs[(wn*64 + nt*16 + (lane & 15))*32 + (lane >> 4)*8];
        #pragma unroll
        for (int mt = 0; mt < 4; ++mt)
            #pragma unroll
            for (int nt = 0; nt < 4; ++nt)
                acc[mt][nt] = mfma16(af[mt], bfr[nt], acc[mt][nt]);
        __syncthreads();
    }
    int mlo = bm*128 + wm*64;
    int nlo = bn*128 + wn*64;
    #pragma unroll
    for (int mt = 0; mt < 4; ++mt) {
        #pragma unroll
        for (int nt = 0; nt < 4; ++nt) {
            int n = nlo + nt*16 + (lane & 15);
            float bias = bo[n];
            #pragma unroll
            for (int r = 0; r < 4; ++r) {
                int m = mlo + mt*16 + (lane >> 4)*4 + r;
                out[(long)m*D_ + n] = acc[mt][nt][r] + bias;
            }
        }
    }
}

extern "C" void kernel_launch(void* const* d_in, const int* in_sizes, int n_in,
                              void* d_out, int out_size, void* d_ws, size_t ws_size,
                              hipStream_t stream) {
    const float* x  = (const float*)d_in[0];
    const float* Wq = (const float*)d_in[1];
    const float* Wk = (const float*)d_in[2];
    const float* Wv = (const float*)d_in[3];
    const float* Wo = (const float*)d_in[4];
    const float* bo = (const float*)d_in[5];
    float* out = (float*)d_out;

    bf16* ws  = (bf16*)d_ws;
    bf16* xb  = ws;                    // 8388608 elems [B*T, D], later reused as attn output O
    bf16* wqb = ws + 8388608L;         // 4194304 each
    bf16* wkb = ws + 12582912L;
    bf16* wvb = ws + 16777216L;
    bf16* wob = ws + 20971520L;
    bf16* Qb  = ws + 25165824L;        // [B,H,T,HD] 8388608 each
    bf16* Kb  = ws + 33554432L;
    bf16* Vb  = ws + 41943040L;
    bf16* Ob  = xb;                    // reuse (xb dead after gemm_qkv)

    cast6<<<dim3(2048, 6), 256, 0, stream>>>(x, x + 4194304L, Wq, Wk, Wv, Wo, ws);
    gemm_qkv<<<dim3(16, 32, 3), 256, 0, stream>>>(xb, wqb, wkb, wvb, Qb, Kb, Vb);
    attn<<<512, 256, 0, stream>>>(Qb, Kb, Vb, Ob);
    gemm_out<<<dim3(16, 32), 256, 0, stream>>>(Ob, wob, bo, out);
}